// Round 3
// baseline (139.713 us; speedup 1.0000x reference)
//
#include <hip/hip_runtime.h>
#include <math.h>

#define B_  2048
#define T_  200
#define D_  64
#define H1_ 80
#define H2_ 40

#define KSTR 72    // K-tile row stride (bf16 elems): 144 B rows -> ~2-way banks
#define HSTR 104   // h1 row stride: 208 B rows -> ~2-way banks, holds K=96 padded

typedef __bf16 bf16x8 __attribute__((ext_vector_type(8)));
typedef __bf16 bf16x4 __attribute__((ext_vector_type(4)));
typedef float  f32x4  __attribute__((ext_vector_type(4)));

__device__ __forceinline__ float sigmoidf_(float x) { return 1.0f / (1.0f + __expf(-x)); }

__global__ __launch_bounds__(256, 4)
void attn_din_mfma2(const float* __restrict__ query,
                    const float* __restrict__ key,
                    const int*   __restrict__ mask,
                    const float* __restrict__ W1,
                    const float* __restrict__ b1,
                    const float* __restrict__ W2,
                    const float* __restrict__ b2,
                    const float* __restrict__ W3,
                    const float* __restrict__ b3,
                    float* __restrict__ out)
{
    // union: K-tile [128][KSTR] bf16  <->  h1 [128][HSTR] bf16  <->  s_part (epilogue)
    __shared__ __bf16 s_KH[128 * HSTR];     // 26624 B
    __shared__ __bf16 s_V[H1_ * KSTR];      // 11520 B
    __shared__ float  s_q[D_];
    __shared__ float  s_base[H1_];
    __shared__ float  s_W3[48];
    __shared__ float  s_b2[48];
    __shared__ float  s_scf[256];
    __shared__ float  s_red[8];
    // total ~40160 B -> 4 blocks/CU

    const int b    = blockIdx.x;
    const int tid  = threadIdx.x;
    const int lane = tid & 63;
    const int w    = tid >> 6;     // wave 0..3: owns local rows w*32 .. w*32+31 per pass
    const int c16  = lane & 15;
    const int g16  = lane >> 4;

    const int   mv  = mask[b];
    const float b3v = b3[0];
    const float* kb = key + (size_t)b * T_ * D_;

    // ---------------- phase 1: small stages + K-tile pass 0 (rows 0..127) ----------------
    if (tid < D_) s_q[tid] = query[b * D_ + tid];
    if (tid < 48) {
        s_W3[tid] = (tid < H2_) ? W3[tid] : 0.0f;
        s_b2[tid] = (tid < H2_) ? b2[tid] : 0.0f;
    }
    s_scf[tid] = -1e30f;

    #pragma unroll
    for (int i = 0; i < 8; ++i) {
        int e = tid + 256 * i;               // 128 rows * 16 float4
        int row = e >> 4, c4 = e & 15;
        float4 v = *(const float4*)(kb + row * D_ + c4 * 4);
        bf16x4 pk;
        pk[0] = (__bf16)v.x; pk[1] = (__bf16)v.y; pk[2] = (__bf16)v.z; pk[3] = (__bf16)v.w;
        *(bf16x4*)&s_KH[row * KSTR + c4 * 4] = pk;
    }
    __syncthreads();

    // ---------------- phase 2: collapsed weights V[h][f], base[h] ----------------
    // din=[q,k,q-k,q*k] => pre1[t][h] = base[h] + sum_f k[t][f]*V[h][f]
    #pragma unroll
    for (int i = 0; i < 20; ++i) {
        int e = tid + 256 * i;               // 5120 exactly
        int h = e % H1_, f = e / H1_;
        float v = W1[(64 + f) * H1_ + h] - W1[(128 + f) * H1_ + h]
                + s_q[f] * W1[(192 + f) * H1_ + h];
        s_V[h * KSTR + f] = (__bf16)v;
    }
    if (tid < H1_) {
        float a = b1[tid];
        for (int f = 0; f < D_; ++f)
            a = fmaf(s_q[f], W1[f * H1_ + tid] + W1[(128 + f) * H1_ + tid], a);
        s_base[tid] = a;
    }
    __syncthreads();

    // ---------------- two passes over T: rows [0,128) and [128,256) ----------------
    for (int p = 0; p < 2; ++p) {
        // fragment reads (A from K-tile: own wave's rows only; B from s_V)
        bf16x8 af[2][2], bf[5][2];
        #pragma unroll
        for (int mt = 0; mt < 2; ++mt)
            #pragma unroll
            for (int ks = 0; ks < 2; ++ks)
                af[mt][ks] = *(const bf16x8*)&s_KH[((w * 2 + mt) * 16 + c16) * KSTR + ks * 32 + g16 * 8];
        #pragma unroll
        for (int nt = 0; nt < 5; ++nt)
            #pragma unroll
            for (int ks = 0; ks < 2; ++ks)
                bf[nt][ks] = *(const bf16x8*)&s_V[(nt * 16 + c16) * KSTR + ks * 32 + g16 * 8];
        __syncthreads();   // all K-tile reads done; s_KH may be rewritten as h1

        // layer 1 (per-mt streaming): acc initialized to base -> sigmoid -> h1 (bf16, stride HSTR)
        #pragma unroll
        for (int mt = 0; mt < 2; ++mt) {
            int tb = p * 128 + (w * 2 + mt) * 16;
            if (tb < T_) {
                f32x4 acc[5];
                #pragma unroll
                for (int nt = 0; nt < 5; ++nt) {
                    float bb = s_base[nt * 16 + c16];
                    f32x4 c = { bb, bb, bb, bb };
                    c = __builtin_amdgcn_mfma_f32_16x16x32_bf16(af[mt][0], bf[nt][0], c, 0, 0, 0);
                    c = __builtin_amdgcn_mfma_f32_16x16x32_bf16(af[mt][1], bf[nt][1], c, 0, 0, 0);
                    acc[nt] = c;
                }
                #pragma unroll
                for (int nt = 0; nt < 5; ++nt)
                    #pragma unroll
                    for (int r = 0; r < 4; ++r) {
                        int rl = (w * 2 + mt) * 16 + g16 * 4 + r;   // local row
                        s_KH[rl * HSTR + nt * 16 + c16] = (__bf16)sigmoidf_(acc[nt][r]);
                    }
            }
        }
        // zero-pad h1 cols 80..95 of own rows (only if any own tile live)
        if (p * 128 + w * 32 < T_) {
            int rl = w * 32 + (lane >> 1);
            *(uint4*)&s_KH[rl * HSTR + 80 + (lane & 1) * 8] = make_uint4(0, 0, 0, 0);
        }

        // layer 2 B-fragments straight from global (W2 is L2-resident, block-invariant)
        bf16x8 bw[3][3];
        #pragma unroll
        for (int nt = 0; nt < 3; ++nt)
            #pragma unroll
            for (int ks = 0; ks < 3; ++ks) {
                int g = nt * 16 + c16;
                #pragma unroll
                for (int j = 0; j < 8; ++j) {
                    int h = ks * 32 + g16 * 8 + j;
                    float v = (g < H2_ && h < H1_) ? W2[h * H2_ + g] : 0.0f;
                    bw[nt][ks][j] = (__bf16)v;
                }
            }
        float w3c[3] = { s_W3[c16], s_W3[16 + c16], s_W3[32 + c16] };

        // layer 2 + layer 3 (wave-local h1 read; compiler inserts lgkmcnt)
        #pragma unroll
        for (int mt = 0; mt < 2; ++mt) {
            int tb = p * 128 + (w * 2 + mt) * 16;
            if (tb < T_) {
                bf16x8 a2[3];
                #pragma unroll
                for (int ks = 0; ks < 3; ++ks)
                    a2[ks] = *(const bf16x8*)&s_KH[((w * 2 + mt) * 16 + c16) * HSTR + ks * 32 + g16 * 8];
                f32x4 acc2[3];
                #pragma unroll
                for (int nt = 0; nt < 3; ++nt) {
                    float bb = s_b2[nt * 16 + c16];
                    f32x4 c = { bb, bb, bb, bb };
                    c = __builtin_amdgcn_mfma_f32_16x16x32_bf16(a2[0], bw[nt][0], c, 0, 0, 0);
                    c = __builtin_amdgcn_mfma_f32_16x16x32_bf16(a2[1], bw[nt][1], c, 0, 0, 0);
                    c = __builtin_amdgcn_mfma_f32_16x16x32_bf16(a2[2], bw[nt][2], c, 0, 0, 0);
                    acc2[nt] = c;
                }
                #pragma unroll
                for (int r = 0; r < 4; ++r) {
                    float partial = sigmoidf_(acc2[0][r]) * w3c[0]
                                  + sigmoidf_(acc2[1][r]) * w3c[1]
                                  + sigmoidf_(acc2[2][r]) * w3c[2];
                    partial += __shfl_xor(partial, 1);
                    partial += __shfl_xor(partial, 2);
                    partial += __shfl_xor(partial, 4);
                    partial += __shfl_xor(partial, 8);
                    if (c16 == 0) {
                        int t = tb + g16 * 4 + r;
                        float sc = (partial + b3v) * 0.125f;   // / sqrt(64)
                        s_scf[t] = (t < mv) ? sc : -1e30f;
                    }
                }
            }
        }
        __syncthreads();

        // stage K for pass 1 (rows 128..199; rows >=200 left as garbage, tiles skipped/masked)
        if (p == 0) {
            #pragma unroll
            for (int i = 0; i < 8; ++i) {
                int e = tid + 256 * i;
                int row = e >> 4, c4 = e & 15;
                int grow = 128 + row;
                if (grow < T_) {
                    float4 v = *(const float4*)(kb + grow * D_ + c4 * 4);
                    bf16x4 pk;
                    pk[0] = (__bf16)v.x; pk[1] = (__bf16)v.y; pk[2] = (__bf16)v.z; pk[3] = (__bf16)v.w;
                    *(bf16x4*)&s_KH[row * KSTR + c4 * 4] = pk;
                }
            }
            __syncthreads();
        }
    }

    // ---------------- softmax over 256 slots ----------------
    float score = s_scf[tid];
    float v = score;
    #pragma unroll
    for (int off = 32; off >= 1; off >>= 1) v = fmaxf(v, __shfl_xor(v, off));
    if (lane == 0) s_red[w] = v;
    __syncthreads();
    float m = fmaxf(fmaxf(s_red[0], s_red[1]), fmaxf(s_red[2], s_red[3]));
    float pexp = __expf(score - m);
    float ps = pexp;
    #pragma unroll
    for (int off = 32; off >= 1; off >>= 1) ps += __shfl_xor(ps, off);
    if (lane == 0) s_red[4 + w] = ps;
    s_scf[tid] = pexp;
    __syncthreads();
    float inv_total = 1.0f / (s_red[4] + s_red[5] + s_red[6] + s_red[7]);

    // ---------------- weighted sum: out[b][d] = sum_t p[t]*key[b][t][d] ----------------
    float* s_part = (float*)s_KH;            // s_KH dead now
    float acc = 0.0f;
    for (int t = w * 50; t < w * 50 + 50; ++t)
        acc = fmaf(s_scf[t], kb[t * D_ + lane], acc);
    s_part[w * 64 + lane] = acc;
    __syncthreads();
    if (tid < D_) {
        float r = (s_part[0 * 64 + tid] + s_part[1 * 64 + tid] +
                   s_part[2 * 64 + tid] + s_part[3 * 64 + tid]) * inv_total;
        out[b * D_ + tid] = r;
    }
}

extern "C" void kernel_launch(void* const* d_in, const int* in_sizes, int n_in,
                              void* d_out, int out_size, void* d_ws, size_t ws_size,
                              hipStream_t stream)
{
    const float* query = (const float*)d_in[0];
    const float* key   = (const float*)d_in[1];
    const int*   mask  = (const int*)  d_in[2];
    const float* W1    = (const float*)d_in[3];
    const float* b1    = (const float*)d_in[4];
    const float* W2    = (const float*)d_in[5];
    const float* b2    = (const float*)d_in[6];
    const float* W3    = (const float*)d_in[7];
    const float* b3    = (const float*)d_in[8];
    float* out = (float*)d_out;

    attn_din_mfma2<<<B_, 256, 0, stream>>>(query, key, mask, W1, b1, W2, b2, W3, b3, out);
}

// Round 4
// 94.305 us; speedup vs baseline: 1.4815x; 1.4815x over previous
//
#include <hip/hip_runtime.h>
#include <math.h>

#define B_  2048
#define T_  200
#define D_  64
#define H1_ 80
#define H2_ 40

#define VSTR 72   // s_V row stride (bf16): 144 B -> 2-way banks on 16-row b128 reads
#define HSTR 88   // h1 row stride (bf16): 176 B -> 2-way banks, 16B-aligned rows

typedef __bf16 bf16x8 __attribute__((ext_vector_type(8)));
typedef float  f32x4  __attribute__((ext_vector_type(4)));

__device__ __forceinline__ float sigmoidf_(float x) { return 1.0f / (1.0f + __expf(-x)); }

__global__ __launch_bounds__(256, 4)
void attn_din3(const float* __restrict__ query,
               const float* __restrict__ key,
               const int*   __restrict__ mask,
               const float* __restrict__ W1,
               const float* __restrict__ b1,
               const float* __restrict__ W2,
               const float* __restrict__ b2,
               const float* __restrict__ W3,
               const float* __restrict__ b3,
               float* __restrict__ out)
{
    __shared__ __bf16 s_V[H1_ * VSTR];      // 11520 B  V[h][f]
    __shared__ __bf16 s_h1[4][16 * HSTR];   // 11264 B  per-wave h1 tile
    __shared__ float  s_q[D_];
    __shared__ float  s_base[H1_];
    __shared__ float  s_W3[48];
    __shared__ float  s_b2[48];
    __shared__ float  s_scf[256];
    __shared__ float  s_red[8];
    // ~25.4 KB total

    const int b    = blockIdx.x;
    const int tid  = threadIdx.x;
    const int lane = tid & 63;
    const int w    = tid >> 6;
    const int c16  = lane & 15;
    const int g16  = lane >> 4;

    const int   mv  = mask[b];
    const float b3v = b3[0];
    const float* kb = key + (size_t)b * T_ * D_;

    // ---------------- stage small data ----------------
    if (tid < D_) s_q[tid] = query[b * D_ + tid];
    if (tid < 48) {
        s_W3[tid] = (tid < H2_) ? W3[tid] : 0.0f;
        s_b2[tid] = (tid < H2_) ? b2[tid] : 0.0f;
    }
    s_scf[tid] = -1e30f;
    __syncthreads();

    // ---------------- collapsed weights: V[h][f], base[h] ----------------
    // din=[q,k,q-k,q*k] => pre1[t][h] = base[h] + sum_f k[t][f]*V[h][f]
    #pragma unroll
    for (int i = 0; i < 20; ++i) {
        int e = tid + 256 * i;              // 5120 exactly
        int h = e % H1_, f = e / H1_;
        float v = W1[(64 + f) * H1_ + h] - W1[(128 + f) * H1_ + h]
                + s_q[f] * W1[(192 + f) * H1_ + h];
        s_V[h * VSTR + f] = (__bf16)v;
    }
    if (tid < H1_) {
        float a = b1[tid];
        #pragma unroll 8
        for (int f = 0; f < D_; ++f)
            a = fmaf(s_q[f], W1[f * H1_ + tid] + W1[(128 + f) * H1_ + tid], a);
        s_base[tid] = a;
    }
    __syncthreads();

    // ---------------- W2T fragments in registers (W2 small, L2-resident) ----------------
    bf16x8 bw[3][3];
    #pragma unroll
    for (int nt = 0; nt < 3; ++nt) {
        int g = nt * 16 + c16;
        #pragma unroll
        for (int ks = 0; ks < 3; ++ks)
            #pragma unroll
            for (int j = 0; j < 8; ++j) {
                int h = ks * 32 + g16 * 8 + j;
                bw[nt][ks][j] = (g < H2_ && h < H1_) ? (__bf16)W2[h * H2_ + g] : (__bf16)0.0f;
            }
    }
    const float w3c0 = s_W3[c16], w3c1 = s_W3[16 + c16], w3c2 = s_W3[32 + c16];
    __bf16* myh = &s_h1[w][0];

    // ---------------- main loop: wave-independent 16-row tiles, no barriers ----------------
    for (int tt = w; tt < 13; tt += 4) {
        const int tb = tt * 16;
        // A fragments straight from global (f32 -> bf16); clamp rows >= 200
        const int trow = tb + c16;
        const float* krow = kb + (size_t)((trow < T_) ? trow : (T_ - 1)) * D_ + g16 * 8;
        bf16x8 af0, af1;
        {
            float4 u0 = *(const float4*)(krow);
            float4 u1 = *(const float4*)(krow + 4);
            float4 u2 = *(const float4*)(krow + 32);
            float4 u3 = *(const float4*)(krow + 36);
            af0[0] = (__bf16)u0.x; af0[1] = (__bf16)u0.y; af0[2] = (__bf16)u0.z; af0[3] = (__bf16)u0.w;
            af0[4] = (__bf16)u1.x; af0[5] = (__bf16)u1.y; af0[6] = (__bf16)u1.z; af0[7] = (__bf16)u1.w;
            af1[0] = (__bf16)u2.x; af1[1] = (__bf16)u2.y; af1[2] = (__bf16)u2.z; af1[3] = (__bf16)u2.w;
            af1[4] = (__bf16)u3.x; af1[5] = (__bf16)u3.y; af1[6] = (__bf16)u3.z; af1[7] = (__bf16)u3.w;
        }

        // layer 1: acc init to base, per-nt streamed B frags
        f32x4 acc[5];
        #pragma unroll
        for (int nt = 0; nt < 5; ++nt) {
            float bb = s_base[nt * 16 + c16];
            f32x4 c = { bb, bb, bb, bb };
            bf16x8 b0 = *(const bf16x8*)&s_V[(nt * 16 + c16) * VSTR + g16 * 8];
            bf16x8 b1v = *(const bf16x8*)&s_V[(nt * 16 + c16) * VSTR + 32 + g16 * 8];
            c = __builtin_amdgcn_mfma_f32_16x16x32_bf16(af0, b0, c, 0, 0, 0);
            c = __builtin_amdgcn_mfma_f32_16x16x32_bf16(af1, b1v, c, 0, 0, 0);
            acc[nt] = c;
        }
        // sigmoid -> own-wave h1 tile (transpose via LDS; same-wave, lgkmcnt only)
        #pragma unroll
        for (int nt = 0; nt < 5; ++nt)
            #pragma unroll
            for (int r = 0; r < 4; ++r)
                myh[(g16 * 4 + r) * HSTR + nt * 16 + c16] = (__bf16)sigmoidf_(acc[nt][r]);

        // layer 2 A frags (k = h dim; ks=2 valid only for g16<2 -> zero guard)
        bf16x8 a2_0 = *(const bf16x8*)&myh[c16 * HSTR + g16 * 8];
        bf16x8 a2_1 = *(const bf16x8*)&myh[c16 * HSTR + 32 + g16 * 8];
        bf16x8 a2_2;
        #pragma unroll
        for (int j = 0; j < 8; ++j) a2_2[j] = (__bf16)0.0f;
        if (g16 < 2) a2_2 = *(const bf16x8*)&myh[c16 * HSTR + 64 + g16 * 8];

        f32x4 acc2[3];
        #pragma unroll
        for (int nt = 0; nt < 3; ++nt) {
            float bb = s_b2[nt * 16 + c16];
            f32x4 c = { bb, bb, bb, bb };
            c = __builtin_amdgcn_mfma_f32_16x16x32_bf16(a2_0, bw[nt][0], c, 0, 0, 0);
            c = __builtin_amdgcn_mfma_f32_16x16x32_bf16(a2_1, bw[nt][1], c, 0, 0, 0);
            c = __builtin_amdgcn_mfma_f32_16x16x32_bf16(a2_2, bw[nt][2], c, 0, 0, 0);
            acc2[nt] = c;
        }

        // layer 3 + score (reduce over 16 g-lanes)
        #pragma unroll
        for (int r = 0; r < 4; ++r) {
            float partial = sigmoidf_(acc2[0][r]) * w3c0
                          + sigmoidf_(acc2[1][r]) * w3c1
                          + sigmoidf_(acc2[2][r]) * w3c2;
            partial += __shfl_xor(partial, 1);
            partial += __shfl_xor(partial, 2);
            partial += __shfl_xor(partial, 4);
            partial += __shfl_xor(partial, 8);
            int t = tb + g16 * 4 + r;
            if (c16 == 0 && t < mv)
                s_scf[t] = (partial + b3v) * 0.125f;   // / sqrt(64); t>=mv stays -1e30
        }
    }
    __syncthreads();

    // ---------------- softmax over 256 slots ----------------
    float score = s_scf[tid];
    float v = score;
    #pragma unroll
    for (int off = 32; off >= 1; off >>= 1) v = fmaxf(v, __shfl_xor(v, off));
    if (lane == 0) s_red[w] = v;
    __syncthreads();
    float m = fmaxf(fmaxf(s_red[0], s_red[1]), fmaxf(s_red[2], s_red[3]));
    float pexp = __expf(score - m);
    float ps = pexp;
    #pragma unroll
    for (int off = 32; off >= 1; off >>= 1) ps += __shfl_xor(ps, off);
    if (lane == 0) s_red[4 + w] = ps;
    s_scf[tid] = pexp;
    __syncthreads();
    float inv_total = 1.0f / (s_red[4] + s_red[5] + s_red[6] + s_red[7]);

    // ---------------- weighted sum: out[b][d] = sum_t p[t]*key[b][t][d] ----------------
    float* s_part = (float*)&s_h1[0][0];    // h1 dead now
    float acc = 0.0f;
    #pragma unroll 10
    for (int t = w * 50; t < w * 50 + 50; ++t)
        acc = fmaf(s_scf[t], kb[t * D_ + lane], acc);
    s_part[w * 64 + lane] = acc;
    __syncthreads();
    if (tid < D_) {
        float r = (s_part[0 * 64 + tid] + s_part[1 * 64 + tid] +
                   s_part[2 * 64 + tid] + s_part[3 * 64 + tid]) * inv_total;
        out[b * D_ + tid] = r;
    }
}

extern "C" void kernel_launch(void* const* d_in, const int* in_sizes, int n_in,
                              void* d_out, int out_size, void* d_ws, size_t ws_size,
                              hipStream_t stream)
{
    const float* query = (const float*)d_in[0];
    const float* key   = (const float*)d_in[1];
    const int*   mask  = (const int*)  d_in[2];
    const float* W1    = (const float*)d_in[3];
    const float* b1    = (const float*)d_in[4];
    const float* W2    = (const float*)d_in[5];
    const float* b2    = (const float*)d_in[6];
    const float* W3    = (const float*)d_in[7];
    const float* b3    = (const float*)d_in[8];
    float* out = (float*)d_out;

    attn_din3<<<B_, 256, 0, stream>>>(query, key, mask, W1, b1, W2, b2, W3, b3, out);
}

// Round 5
// 92.414 us; speedup vs baseline: 1.5118x; 1.0205x over previous
//
#include <hip/hip_runtime.h>
#include <math.h>

#define B_  2048
#define T_  200
#define D_  64
#define H1_ 80
#define H2_ 40

#define VSTR 72    // s_V row stride (bf16): 144 B rows -> ~2-way banks
#define WSTR 104   // W2T row stride (bf16): 208 B rows -> ~2-way banks
#define HSTR 104   // h1 row stride (bf16): 208 B rows; cols 80..103 zero pad

typedef __bf16 bf16x8 __attribute__((ext_vector_type(8)));
typedef float  f32x4  __attribute__((ext_vector_type(4)));

__device__ __forceinline__ float sigmoidf_(float x) {
    return __builtin_amdgcn_rcpf(1.0f + __expf(-x));
}

__global__ __launch_bounds__(256, 4)
void attn_din4(const float* __restrict__ query,
               const float* __restrict__ key,
               const int*   __restrict__ mask,
               const float* __restrict__ W1,
               const float* __restrict__ b1,
               const float* __restrict__ W2,
               const float* __restrict__ b2,
               const float* __restrict__ W3,
               const float* __restrict__ b3,
               float* __restrict__ out)
{
    __shared__ __bf16 s_V[H1_ * VSTR];       // 11520 B   V[h][f]
    __shared__ __bf16 s_W2T[48 * WSTR];      //  9984 B   W2T[g][h], zero-padded
    __shared__ __bf16 s_h1[4][16 * HSTR];    // 13312 B   per-wave h1 tile
    __shared__ float  s_q[D_];
    __shared__ float  s_base[H1_];
    __shared__ float  s_W3[48];
    __shared__ float  s_b2[48];
    __shared__ float  s_scf[256];
    __shared__ float  s_red[8];
    // ~37.1 KB -> 4 blocks/CU

    const int b    = blockIdx.x;
    const int tid  = threadIdx.x;
    const int lane = tid & 63;
    const int w    = tid >> 6;
    const int c16  = lane & 15;
    const int g16  = lane >> 4;

    const int   mv  = mask[b];
    const float b3v = b3[0];
    const float* kb = key + (size_t)b * T_ * D_;

    // ---------------- stage small data ----------------
    if (tid < D_) s_q[tid] = query[b * D_ + tid];
    if (tid < 48) {
        s_W3[tid] = (tid < H2_) ? W3[tid] : 0.0f;
        s_b2[tid] = (tid < H2_) ? b2[tid] : 0.0f;
    }
    s_scf[tid] = -1e30f;

    // W2T staging with incremental (g,h) update: 48*104 = 4992 elems
    {
        int g = tid / WSTR, h = tid - g * WSTR;
        #pragma unroll
        for (int i = 0; i < 20; ++i) {
            int e = tid + 256 * i;
            if (e < 48 * WSTR) {
                float v = (g < H2_ && h < H1_) ? W2[h * H2_ + g] : 0.0f;
                s_W2T[g * WSTR + h] = (__bf16)v;
            }
            h += 48; g += 2;                  // 256 = 2*104 + 48
            if (h >= WSTR) { h -= WSTR; g += 1; }
        }
    }
    __syncthreads();

    // ---------------- collapsed weights: V[h][f], base[h] ----------------
    // din=[q,k,q-k,q*k] => pre1[t][h] = base[h] + sum_f k[t][f]*V[h][f]
    {
        int h = tid & 63;  int f0 = tid >> 6;                 // start: e=tid: h=tid%80? no:
        // use exact divmod once (tid<256, H1=80): h = tid%80, f = tid/80
        int f = tid / H1_;  h = tid - f * H1_;
        #pragma unroll
        for (int i = 0; i < 20; ++i) {                        // 5120 exactly
            float v = W1[(64 + f) * H1_ + h] - W1[(128 + f) * H1_ + h]
                    + s_q[f] * W1[(192 + f) * H1_ + h];
            s_V[h * VSTR + f] = (__bf16)v;
            h += 16; f += 3;                                  // 256 = 3*80 + 16
            if (h >= H1_) { h -= H1_; f += 1; }
        }
        (void)f0;
    }
    if (tid < H1_) {
        float a = b1[tid];
        #pragma unroll 8
        for (int f = 0; f < D_; ++f)
            a = fmaf(s_q[f], W1[f * H1_ + tid] + W1[(128 + f) * H1_ + tid], a);
        s_base[tid] = a;
    }
    // zero-fill h1 pad cols 80..95 once (each wave its own tile; never rewritten)
    {
        uint2 z = make_uint2(0u, 0u);
        int row = lane & 15, c0 = 80 + (lane >> 4) * 4;
        *(uint2*)&s_h1[w][row * HSTR + c0] = z;
    }
    __syncthreads();

    // ---------------- hoisted loop-invariant scalars ----------------
    float base_c[5], b2c[3];
    #pragma unroll
    for (int nt = 0; nt < 5; ++nt) base_c[nt] = s_base[nt * 16 + c16];
    #pragma unroll
    for (int nt = 0; nt < 3; ++nt) b2c[nt] = s_b2[nt * 16 + c16];
    const float w3c0 = s_W3[c16], w3c1 = s_W3[16 + c16], w3c2 = s_W3[32 + c16];
    __bf16* myh = &s_h1[w][0];

    // ---------------- main loop: wave-independent 16-row tiles, no barriers ----------------
    for (int tt = w; tt < 13; tt += 4) {
        const int tb = tt * 16;
        const int trow = tb + c16;
        const float* krow = kb + (size_t)((trow < T_) ? trow : (T_ - 1)) * D_ + g16 * 8;
        bf16x8 af0, af1;
        {
            float4 u0 = *(const float4*)(krow);
            float4 u1 = *(const float4*)(krow + 4);
            float4 u2 = *(const float4*)(krow + 32);
            float4 u3 = *(const float4*)(krow + 36);
            af0[0] = (__bf16)u0.x; af0[1] = (__bf16)u0.y; af0[2] = (__bf16)u0.z; af0[3] = (__bf16)u0.w;
            af0[4] = (__bf16)u1.x; af0[5] = (__bf16)u1.y; af0[6] = (__bf16)u1.z; af0[7] = (__bf16)u1.w;
            af1[0] = (__bf16)u2.x; af1[1] = (__bf16)u2.y; af1[2] = (__bf16)u2.z; af1[3] = (__bf16)u2.w;
            af1[4] = (__bf16)u3.x; af1[5] = (__bf16)u3.y; af1[6] = (__bf16)u3.z; af1[7] = (__bf16)u3.w;
        }

        // layer 1: acc init to base; B frags streamed from LDS per nt
        #pragma unroll
        for (int nt = 0; nt < 5; ++nt) {
            float bb = base_c[nt];
            f32x4 c = { bb, bb, bb, bb };
            bf16x8 b0  = *(const bf16x8*)&s_V[(nt * 16 + c16) * VSTR + g16 * 8];
            bf16x8 b1v = *(const bf16x8*)&s_V[(nt * 16 + c16) * VSTR + 32 + g16 * 8];
            c = __builtin_amdgcn_mfma_f32_16x16x32_bf16(af0, b0, c, 0, 0, 0);
            c = __builtin_amdgcn_mfma_f32_16x16x32_bf16(af1, b1v, c, 0, 0, 0);
            #pragma unroll
            for (int r = 0; r < 4; ++r)
                myh[(g16 * 4 + r) * HSTR + nt * 16 + c16] = (__bf16)sigmoidf_(c[r]);
        }

        // layer 2: A frags from own h1 tile (k=0..95, pad zeroed), B from s_W2T
        bf16x8 a2_0 = *(const bf16x8*)&myh[c16 * HSTR + g16 * 8];
        bf16x8 a2_1 = *(const bf16x8*)&myh[c16 * HSTR + 32 + g16 * 8];
        bf16x8 a2_2 = *(const bf16x8*)&myh[c16 * HSTR + 64 + g16 * 8];

        f32x4 acc2[3];
        #pragma unroll
        for (int nt = 0; nt < 3; ++nt) {
            float bb = b2c[nt];
            f32x4 c = { bb, bb, bb, bb };
            bf16x8 w0 = *(const bf16x8*)&s_W2T[(nt * 16 + c16) * WSTR + g16 * 8];
            bf16x8 w1 = *(const bf16x8*)&s_W2T[(nt * 16 + c16) * WSTR + 32 + g16 * 8];
            bf16x8 w2 = *(const bf16x8*)&s_W2T[(nt * 16 + c16) * WSTR + 64 + g16 * 8];
            c = __builtin_amdgcn_mfma_f32_16x16x32_bf16(a2_0, w0, c, 0, 0, 0);
            c = __builtin_amdgcn_mfma_f32_16x16x32_bf16(a2_1, w1, c, 0, 0, 0);
            c = __builtin_amdgcn_mfma_f32_16x16x32_bf16(a2_2, w2, c, 0, 0, 0);
            acc2[nt] = c;
        }

        // layer 3 + score (reduce over 16 c-lanes)
        #pragma unroll
        for (int r = 0; r < 4; ++r) {
            float partial = sigmoidf_(acc2[0][r]) * w3c0
                          + sigmoidf_(acc2[1][r]) * w3c1
                          + sigmoidf_(acc2[2][r]) * w3c2;
            partial += __shfl_xor(partial, 1);
            partial += __shfl_xor(partial, 2);
            partial += __shfl_xor(partial, 4);
            partial += __shfl_xor(partial, 8);
            int t = tb + g16 * 4 + r;
            if (c16 == 0 && t < mv)
                s_scf[t] = (partial + b3v) * 0.125f;   // / sqrt(64); masked stay -1e30
        }
    }
    __syncthreads();

    // ---------------- softmax over 256 slots ----------------
    float score = s_scf[tid];
    float v = score;
    #pragma unroll
    for (int off = 32; off >= 1; off >>= 1) v = fmaxf(v, __shfl_xor(v, off));
    if (lane == 0) s_red[w] = v;
    __syncthreads();
    float m = fmaxf(fmaxf(s_red[0], s_red[1]), fmaxf(s_red[2], s_red[3]));
    float pexp = __expf(score - m);
    float ps = pexp;
    #pragma unroll
    for (int off = 32; off >= 1; off >>= 1) ps += __shfl_xor(ps, off);
    if (lane == 0) s_red[4 + w] = ps;
    s_scf[tid] = pexp;
    __syncthreads();
    float inv_total = __builtin_amdgcn_rcpf(s_red[4] + s_red[5] + s_red[6] + s_red[7]);

    // ---------------- weighted sum: out[b][d] = sum_t p[t]*key[b][t][d] ----------------
    float* s_part = (float*)&s_h1[0][0];    // h1 dead now
    float acc = 0.0f;
    #pragma unroll 10
    for (int t = w * 50; t < w * 50 + 50; ++t)
        acc = fmaf(s_scf[t], kb[t * D_ + lane], acc);
    s_part[w * 64 + lane] = acc;
    __syncthreads();
    if (tid < D_) {
        float r = (s_part[0 * 64 + tid] + s_part[1 * 64 + tid] +
                   s_part[2 * 64 + tid] + s_part[3 * 64 + tid]) * inv_total;
        out[b * D_ + tid] = r;
    }
}

extern "C" void kernel_launch(void* const* d_in, const int* in_sizes, int n_in,
                              void* d_out, int out_size, void* d_ws, size_t ws_size,
                              hipStream_t stream)
{
    const float* query = (const float*)d_in[0];
    const float* key   = (const float*)d_in[1];
    const int*   mask  = (const int*)  d_in[2];
    const float* W1    = (const float*)d_in[3];
    const float* b1    = (const float*)d_in[4];
    const float* W2    = (const float*)d_in[5];
    const float* b2    = (const float*)d_in[6];
    const float* W3    = (const float*)d_in[7];
    const float* b3    = (const float*)d_in[8];
    float* out = (float*)d_out;

    attn_din4<<<B_, 256, 0, stream>>>(query, key, mask, W1, b1, W2, b2, W3, b3, out);
}